// Round 17
// baseline (1004.675 us; speedup 1.0000x reference)
//
#include <hip/hip_runtime.h>
#include <hip/hip_bf16.h>

#define NB 262144
#define RTILE 64

typedef __bf16 bf16x8 __attribute__((ext_vector_type(8)));
typedef float f32x4 __attribute__((ext_vector_type(4)));

// ---- packed bf16 weight buffer ----
// MFMA layers fragment-ordered: fragment (colTile,ks) at
//   off + ((colTile*KSTRIDE + ks)*64 + lane)*8
// lane's elems: W[col=colTile*16+(lane&15)][k=ks*32+(lane>>4)*8+e].
// Wsig/Wrgb plain row-major.
#define OFF_W0   0        // [256][64]   (K 63->64)
#define OFF_W1   16384    // [256][256]
#define OFF_W2   81920
#define OFF_W3   147456
#define OFF_W4   212992
#define OFF_W5   278528   // [256][320]  (K 319->320; ks 8,9 = x)
#define OFF_W6   360448
#define OFF_W7   425984
#define OFF_WSIG 491520   // [1][256] plain
#define OFF_W8   491776   // [256][256]
#define OFF_W9   557312   // [128][288]  (K 283->288; ks 8 = d)
#define OFF_W10  594176   // [128][128]
#define OFF_W11  610560
#define OFF_W12  626944
#define OFF_WRGB 643328   // [3][128] plain
#define WTOTAL   643712

__device__ __align__(16) unsigned short g_w[WTOTAL];

__device__ __forceinline__ unsigned short f2bfu(float f) {
  __bf16 h = (__bf16)f;
  return __builtin_bit_cast(unsigned short, h);
}
__device__ __forceinline__ float bfu2f(unsigned short u) {
  return (float)__builtin_bit_cast(__bf16, u);
}

// Hand barrier: orders LDS producer->consumer (lgkmcnt(0)) WITHOUT draining
// vmcnt -- cross-layer weight prefetch loads stay in flight.
// sched_barrier(0) fences compiler motion across it (rule #18).
#define LAYER_BARRIER() do { \
  asm volatile("s_waitcnt lgkmcnt(0)\n\ts_barrier" ::: "memory"); \
  __builtin_amdgcn_sched_barrier(0); \
} while (0)

__global__ void prep_kernel(const float* W0, const float* W1, const float* W2,
                            const float* W3, const float* W4, const float* W5,
                            const float* W6, const float* W7, const float* Wsig,
                            const float* W8, const float* W9, const float* W10,
                            const float* W11, const float* W12, const float* Wrgb) {
  const float* srcs[15] = {W0,W1,W2,W3,W4,W5,W6,W7,Wsig,W8,W9,W10,W11,W12,Wrgb};
  const int dsto[16] = {OFF_W0,OFF_W1,OFF_W2,OFF_W3,OFF_W4,OFF_W5,OFF_W6,OFF_W7,
                        OFF_WSIG,OFF_W8,OFF_W9,OFF_W10,OFF_W11,OFF_W12,OFF_WRGB,WTOTAL};
  const int kpad[15] = {64,256,256,256,256,320,256,256,256,256,288,128,128,128,128};
  const int ksrc[15] = {63,256,256,256,256,319,256,256,256,256,283,128,128,128,128};
  int idx = blockIdx.x * blockDim.x + threadIdx.x;
  if (idx >= WTOTAL) return;
  int r = 0;
  for (int i = 1; i < 15; ++i) if (idx >= dsto[i]) r = i;
  int local = idx - dsto[r];
  float v;
  if (r == 8 || r == 14) {             // head weights: plain row-major
    int o = local / kpad[r];
    int k = local - o * kpad[r];
    v = (k < ksrc[r]) ? srcs[r][o * ksrc[r] + k] : 0.0f;
  } else {                             // MFMA layers: fragment-ordered
    const int KS = kpad[r] >> 5;
    int frag = local >> 9;
    int within = local & 511;
    int lane = within >> 3;
    int e = within & 7;
    int colTile = frag / KS;
    int ks = frag - colTile * KS;
    int col = colTile * 16 + (lane & 15);
    int k = ks * 32 + (lane >> 4) * 8 + e;
    v = (k < ksrc[r]) ? srcs[r][col * ksrc[r] + k] : 0.0f;
  }
  g_w[idx] = f2bfu(v);
}

// ---- fused MLP ----
// r12 fragment-ordered LDS + r15 copy-free parity pipeline + bias-folded acc
// + r16 cross-layer weight prefetch with lgkm-only barriers.
// r17: LDS trimmed to 40960 B exactly (H 32768 + union region U 8192) and
// __launch_bounds__(256,4): round-ledger shows the 2nd arg sets achieved
// blocks/CU on this stack (r5: (256,4)@40960 -> 45.8% occ; r7/r8: (256,3)
// even at 38912 -> 32%). Code needs 84 VGPR <= 128 budget (r4 precedent:
// (256,4) compiled clean at VGPR 100) -> no r5-style spill melt expected.
// U layout: x tile (frag-ordered, 8192 B) through L5; after L5 the lower
// 4096 B is re-staged with d (read at L9; L6-L8 barriers give visibility)
// and the upper 4096 B holds Sb(1024)+Rb(3072) (first written at L7/L12).
template<int KSTRIDE, int NT>
__device__ __forceinline__ void prefetch_b0(
    const unsigned short* Wp, bf16x8 (&b)[2][4], int lane, int wid)
{
  const unsigned short* wb = Wp + (size_t)(wid * NT) * KSTRIDE * 512 + lane * 8;
#pragma unroll
  for (int ct = 0; ct < NT; ++ct)
    b[0][ct] = *(const bf16x8*)&wb[(size_t)(ct * KSTRIDE) * 512];
}

template<int KS1, int KSA1, int KS2, int KSA2, int KSTRIDE, int NT>
__device__ __forceinline__ void gemm_compute(
    const unsigned short* A1,
    const unsigned short* A2,
    const unsigned short* Wp,
    const float* bias,
    bf16x8 (&b)[2][4],                  // b[0][0..NT-1] preloaded by caller
    f32x4 (&acc)[4][NT],
    int lane, int wid)
{
  constexpr int KS = KS1 + KS2;
  const int l4 = lane >> 4;
  const unsigned short* wb = Wp + (size_t)(wid * NT) * KSTRIDE * 512 + lane * 8;
  const unsigned short* a1 = A1 + lane * 8;
  const unsigned short* a2 = A2 ? (A2 + lane * 8) : nullptr;

  // bias-folded accumulator init
#pragma unroll
  for (int ct = 0; ct < NT; ++ct) {
    const f32x4 bv = *(const f32x4*)&bias[wid * (NT * 16) + ct * 16 + l4 * 4];
#pragma unroll
    for (int rt = 0; rt < 4; ++rt)
      acc[rt][ct] = bv;
  }

  bf16x8 a[2][4];
#pragma unroll
  for (int rt = 0; rt < 4; ++rt)
    a[0][rt] = *(const bf16x8*)&a1[(rt * KSA1) * 512];

#pragma unroll
  for (int kk = 0; kk < KS; ++kk) {
    // prefetch kk+1 into the other parity slot (no copies, static indices)
    if (kk + 1 < KS) {
#pragma unroll
      for (int ct = 0; ct < NT; ++ct)
        b[(kk + 1) & 1][ct] = *(const bf16x8*)&wb[(size_t)(ct * KSTRIDE + kk + 1) * 512];
#pragma unroll
      for (int rt = 0; rt < 4; ++rt) {
        if (kk + 1 < KS1)
          a[(kk + 1) & 1][rt] = *(const bf16x8*)&a1[(rt * KSA1 + kk + 1) * 512];
        else
          a[(kk + 1) & 1][rt] = *(const bf16x8*)&a2[(rt * KSA2 + (kk + 1 - KS1)) * 512];
      }
    }
    __builtin_amdgcn_s_setprio(1);
#pragma unroll
    for (int rt = 0; rt < 4; ++rt)
#pragma unroll
      for (int ct = 0; ct < NT; ++ct)
        acc[rt][ct] = __builtin_amdgcn_mfma_f32_16x16x32_bf16(
            b[kk & 1][ct], a[kk & 1][rt], acc[rt][ct], 0, 0, 0);
    __builtin_amdgcn_s_setprio(0);
  }
}

// Store acc (already biased) into fragment-ordered H (KSH=8 stride).
template<int NT, bool RELU>
__device__ __forceinline__ void store_acc(
    const f32x4 (&acc)[4][NT],
    unsigned short* Out, int lane, int wid)
{
  const int l15 = lane & 15;
  const int l4  = lane >> 4;
  const int colbase = wid * (NT * 16);
#pragma unroll
  for (int ct = 0; ct < NT; ++ct) {
    const int c0 = colbase + ct * 16 + l4 * 4;
    const int f  = c0 >> 5;
    const int li = l15 + 16 * ((c0 >> 3) & 3);
    const int e0 = c0 & 7;
#pragma unroll
    for (int rt = 0; rt < 4; ++rt) {
      float v0 = acc[rt][ct][0];
      float v1 = acc[rt][ct][1];
      float v2 = acc[rt][ct][2];
      float v3 = acc[rt][ct][3];
      if (RELU) {
        v0 = fmaxf(v0, 0.f); v1 = fmaxf(v1, 0.f);
        v2 = fmaxf(v2, 0.f); v3 = fmaxf(v3, 0.f);
      }
      uint2 u;
      u.x = (unsigned)f2bfu(v0) | ((unsigned)f2bfu(v1) << 16);
      u.y = (unsigned)f2bfu(v2) | ((unsigned)f2bfu(v3) << 16);
      *(uint2*)&Out[(rt * 8 + f) * 512 + li * 8 + e0] = u;
    }
  }
}

// L7 store + fused sigma partials (h7 . Wsig); acc already biased.
__device__ __forceinline__ void store_acc_sigma(
    const f32x4 (&acc)[4][4],
    unsigned short* Out, float* Sb, int lane, int wid)
{
  const int l15 = lane & 15;
  const int l4  = lane >> 4;
  const int colbase = wid * 64;
  float ps[4] = {0.f, 0.f, 0.f, 0.f};
#pragma unroll
  for (int ct = 0; ct < 4; ++ct) {
    const int c0 = colbase + ct * 16 + l4 * 4;
    const int f  = c0 >> 5;
    const int li = l15 + 16 * ((c0 >> 3) & 3);
    const int e0 = c0 & 7;
    const ushort4 wu = *(const ushort4*)&g_w[OFF_WSIG + c0];
    const float w0 = bfu2f(wu.x), w1 = bfu2f(wu.y), w2 = bfu2f(wu.z), w3 = bfu2f(wu.w);
#pragma unroll
    for (int rt = 0; rt < 4; ++rt) {
      float v0 = fmaxf(acc[rt][ct][0], 0.f);
      float v1 = fmaxf(acc[rt][ct][1], 0.f);
      float v2 = fmaxf(acc[rt][ct][2], 0.f);
      float v3 = fmaxf(acc[rt][ct][3], 0.f);
      uint2 u;
      u.x = (unsigned)f2bfu(v0) | ((unsigned)f2bfu(v1) << 16);
      u.y = (unsigned)f2bfu(v2) | ((unsigned)f2bfu(v3) << 16);
      *(uint2*)&Out[(rt * 8 + f) * 512 + li * 8 + e0] = u;
      ps[rt] += bfu2f(f2bfu(v0)) * w0 + bfu2f(f2bfu(v1)) * w1
              + bfu2f(f2bfu(v2)) * w2 + bfu2f(f2bfu(v3)) * w3;
    }
  }
#pragma unroll
  for (int rt = 0; rt < 4; ++rt) {
    ps[rt] += __shfl_xor(ps[rt], 16);
    ps[rt] += __shfl_xor(ps[rt], 32);
  }
  if (l4 == 0) {
#pragma unroll
    for (int rt = 0; rt < 4; ++rt)
      Sb[wid * 64 + rt * 16 + l15] = ps[rt];
  }
}

// L12 epilogue: rgb partials straight from acc2 (already biased).
__device__ __forceinline__ void rgb_partial(
    const f32x4 (&acc)[4][2],
    float* Rb, int lane, int wid)
{
  const int l15 = lane & 15;
  const int l4  = lane >> 4;
  const int colbase = wid * 32;
  float pr[4][3] = {};
#pragma unroll
  for (int ct = 0; ct < 2; ++ct) {
    const int c0 = colbase + ct * 16 + l4 * 4;
    float wf[3][4];
#pragma unroll
    for (int ch = 0; ch < 3; ++ch) {
      const ushort4 wu = *(const ushort4*)&g_w[OFF_WRGB + ch * 128 + c0];
      wf[ch][0] = bfu2f(wu.x); wf[ch][1] = bfu2f(wu.y);
      wf[ch][2] = bfu2f(wu.z); wf[ch][3] = bfu2f(wu.w);
    }
#pragma unroll
    for (int rt = 0; rt < 4; ++rt) {
      float v0 = fmaxf(acc[rt][ct][0], 0.f);
      float v1 = fmaxf(acc[rt][ct][1], 0.f);
      float v2 = fmaxf(acc[rt][ct][2], 0.f);
      float v3 = fmaxf(acc[rt][ct][3], 0.f);
#pragma unroll
      for (int ch = 0; ch < 3; ++ch)
        pr[rt][ch] += v0 * wf[ch][0] + v1 * wf[ch][1] + v2 * wf[ch][2] + v3 * wf[ch][3];
    }
  }
#pragma unroll
  for (int rt = 0; rt < 4; ++rt)
#pragma unroll
    for (int ch = 0; ch < 3; ++ch) {
      pr[rt][ch] += __shfl_xor(pr[rt][ch], 16);
      pr[rt][ch] += __shfl_xor(pr[rt][ch], 32);
    }
  if (l4 == 0) {
#pragma unroll
    for (int rt = 0; rt < 4; ++rt)
#pragma unroll
      for (int ch = 0; ch < 3; ++ch)
        Rb[((wid * 4 + rt) * 3 + ch) * 16 + l15] = pr[rt][ch];
  }
}

__launch_bounds__(256, 4)
__global__ void nerf_main(const float* __restrict__ x, const float* __restrict__ d,
    const float* b0, const float* b1, const float* b2, const float* b3,
    const float* b4, const float* b5, const float* b6, const float* b7,
    const float* bsig, const float* b8, const float* b9, const float* b10,
    const float* b11, const float* b12, const float* brgb,
    float* __restrict__ out)
{
  __shared__ __align__(16) unsigned short H[64 * 256];   // 32768 B, fragment-ordered KSH=8
  __shared__ __align__(16) unsigned short U[64 * 64];    // 8192 B union region
  // U: x tile (frag KSX=2) through L5; then lower 4096 B = d tile (KSD=1),
  //    upper 4096 B = Sb (1024 B) + Rb (3072 B).
  unsigned short* Xb = U;
  unsigned short* Db = U;                    // lower half, re-staged post-L5
  float* Sb = (float*)(U + 2048);            // byte offset 4096
  float* Rb = (float*)(U + 2560);            // byte offset 5120
  // total LDS = 40960 B -> 4 blocks/CU under launch_bounds(256,4)

  const int tid = threadIdx.x;
  const int lane = tid & 63;
  const int wid = tid >> 6;
  const int rowbase = blockIdx.x * RTILE;

  bf16x8 bb[2][4];
  f32x4 acc4[4][4];
  f32x4 acc2[4][2];

  // prefetch W0 kk=0 frags first -- overlaps the staging phase
  prefetch_b0<2,4>(g_w + OFF_W0, bb, lane, wid);

  // ---- stage x tile (fp32 -> bf16, fragment-ordered writes) ----
  {
    const int r = tid >> 2;      // 0..63
    const int sub = tid & 3;
    const int rt = r >> 4;
    const int rl = r & 15;
    const float* xr = x + (size_t)(rowbase + r) * 63;
    for (int j = 0; j < 16; ++j) {
      const int c = sub + j * 4;        // 0..63
      const unsigned short v = (c < 63) ? f2bfu(xr[c]) : (unsigned short)0;
      Xb[(rt * 2 + (c >> 5)) * 512 + (rl + 16 * ((c >> 3) & 3)) * 8 + (c & 7)] = v;
    }
  }
  LAYER_BARRIER();

  // L0: reads Xb only -> write H directly (first writer)
  gemm_compute<2,2,0,0,2,4>(Xb, nullptr, g_w + OFF_W0, b0, bb, acc4, lane, wid);
  prefetch_b0<8,4>(g_w + OFF_W1, bb, lane, wid);
  store_acc<4,true>(acc4, H, lane, wid);
  LAYER_BARRIER();

#define BIG_LAYER(OFFW, BIAS, PF) \
  gemm_compute<8,8,0,0,8,4>(H, nullptr, g_w + OFFW, BIAS, bb, acc4, lane, wid); \
  PF; \
  LAYER_BARRIER(); \
  store_acc<4,true>(acc4, H, lane, wid); \
  LAYER_BARRIER();

  BIG_LAYER(OFF_W1, b1, (prefetch_b0<8,4>(g_w + OFF_W2, bb, lane, wid)))
  BIG_LAYER(OFF_W2, b2, (prefetch_b0<8,4>(g_w + OFF_W3, bb, lane, wid)))
  BIG_LAYER(OFF_W3, b3, (prefetch_b0<8,4>(g_w + OFF_W4, bb, lane, wid)))
  BIG_LAYER(OFF_W4, b4, (prefetch_b0<10,4>(g_w + OFF_W5, bb, lane, wid)))

  // L5: concat [h(256) | x(63)+pad] -> K=320
  gemm_compute<8,8,2,2,10,4>(H, Xb, g_w + OFF_W5, b5, bb, acc4, lane, wid);
  prefetch_b0<8,4>(g_w + OFF_W6, bb, lane, wid);
  LAYER_BARRIER();
  store_acc<4,true>(acc4, H, lane, wid);
  LAYER_BARRIER();

  // ---- Xb dead: stage d into U lower half (read at L9; L6-L8 barriers
  //      give visibility). Hidden under L6 compute. ----
  {
    const int r = tid >> 2;
    const int sub = tid & 3;
    const int rt = r >> 4;
    const int rl = r & 15;
    const float* dr = d + (size_t)(rowbase + r) * 27;
    for (int j = 0; j < 8; ++j) {
      const int c = sub + j * 4;        // 0..31
      const unsigned short v = (c < 27) ? f2bfu(dr[c]) : (unsigned short)0;
      Db[rt * 512 + (rl + 16 * ((c >> 3) & 3)) * 8 + (c & 7)] = v;
    }
  }

  BIG_LAYER(OFF_W6, b6, (prefetch_b0<8,4>(g_w + OFF_W7, bb, lane, wid)))

  // L7 + fused sigma partials (Sb in U upper half -- Xb dead)
  gemm_compute<8,8,0,0,8,4>(H, nullptr, g_w + OFF_W7, b7, bb, acc4, lane, wid);
  prefetch_b0<8,4>(g_w + OFF_W8, bb, lane, wid);
  LAYER_BARRIER();
  store_acc_sigma(acc4, H, Sb, lane, wid);
  LAYER_BARRIER();

  // finish sigma: 64 threads, Sb stable from here on
  if (tid < 64) {
    float s = Sb[tid] + Sb[64 + tid] + Sb[128 + tid] + Sb[192 + tid] + bsig[0];
    float sp = (s > 0.f) ? (s + log1pf(expf(-s))) : log1pf(expf(s));
    out[3 * NB + rowbase + tid] = sp;
  }

  // L8 (bottleneck, no relu)
  gemm_compute<8,8,0,0,8,4>(H, nullptr, g_w + OFF_W8, b8, bb, acc4, lane, wid);
  prefetch_b0<9,2>(g_w + OFF_W9, bb, lane, wid);
  LAYER_BARRIER();
  store_acc<4,false>(acc4, H, lane, wid);
  LAYER_BARRIER();

  // L9: concat [h8(256) | d(27)+pad] -> K=288, N=128 (d from Db)
  gemm_compute<8,8,1,1,9,2>(H, Db, g_w + OFF_W9, b9, bb, acc2, lane, wid);
  prefetch_b0<4,2>(g_w + OFF_W10, bb, lane, wid);
  LAYER_BARRIER();
  store_acc<2,true>(acc2, H, lane, wid);
  LAYER_BARRIER();

#define SMALL_LAYER(OFFW, BIAS, PF) \
  gemm_compute<4,8,0,0,4,2>(H, nullptr, g_w + OFFW, BIAS, bb, acc2, lane, wid); \
  PF; \
  LAYER_BARRIER(); \
  store_acc<2,true>(acc2, H, lane, wid); \
  LAYER_BARRIER();

  SMALL_LAYER(OFF_W10, b10, (prefetch_b0<4,2>(g_w + OFF_W11, bb, lane, wid)))
  SMALL_LAYER(OFF_W11, b11, (prefetch_b0<4,2>(g_w + OFF_W12, bb, lane, wid)))

  // L12 + fused rgb head: h12 never touches LDS (Rb in U upper half)
  gemm_compute<4,8,0,0,4,2>(H, nullptr, g_w + OFF_W12, b12, bb, acc2, lane, wid);
  rgb_partial(acc2, Rb, lane, wid);
  LAYER_BARRIER();

  if (tid < 192) {
    const int r = tid / 3;
    const int ch = tid - r * 3;
    const int rt = r >> 4;
    const int l15r = r & 15;
    float s = brgb[ch];
#pragma unroll
    for (int w = 0; w < 4; ++w)
      s += Rb[((w * 4 + rt) * 3 + ch) * 16 + l15r];
    float val = 1.f / (1.f + expf(-s));
    out[(size_t)(rowbase + r) * 3 + ch] = val;
  }
}

extern "C" void kernel_launch(void* const* d_in, const int* in_sizes, int n_in,
                              void* d_out, int out_size, void* d_ws, size_t ws_size,
                              hipStream_t stream) {
  const float* x    = (const float*)d_in[0];
  const float* dd   = (const float*)d_in[1];
  const float* W0   = (const float*)d_in[2];
  const float* b0   = (const float*)d_in[3];
  const float* W1   = (const float*)d_in[4];
  const float* b1   = (const float*)d_in[5];
  const float* W2   = (const float*)d_in[6];
  const float* b2   = (const float*)d_in[7];
  const float* W3   = (const float*)d_in[8];
  const float* b3   = (const float*)d_in[9];
  const float* W4   = (const float*)d_in[10];
  const float* b4   = (const float*)d_in[11];
  const float* W5   = (const float*)d_in[12];
  const float* b5   = (const float*)d_in[13];
  const float* W6   = (const float*)d_in[14];
  const float* b6   = (const float*)d_in[15];
  const float* W7   = (const float*)d_in[16];
  const float* b7   = (const float*)d_in[17];
  const float* Wsig = (const float*)d_in[18];
  const float* bsig = (const float*)d_in[19];
  const float* W8   = (const float*)d_in[20];
  const float* b8   = (const float*)d_in[21];
  const float* W9   = (const float*)d_in[22];
  const float* b9   = (const float*)d_in[23];
  const float* W10  = (const float*)d_in[24];
  const float* b10  = (const float*)d_in[25];
  const float* W11  = (const float*)d_in[26];
  const float* b11  = (const float*)d_in[27];
  const float* W12  = (const float*)d_in[28];
  const float* b12  = (const float*)d_in[29];
  const float* Wrgb = (const float*)d_in[30];
  const float* brgb = (const float*)d_in[31];

  prep_kernel<<<(WTOTAL + 255) / 256, 256, 0, stream>>>(
      W0, W1, W2, W3, W4, W5, W6, W7, Wsig, W8, W9, W10, W11, W12, Wrgb);

  nerf_main<<<NB / RTILE, 256, 0, stream>>>(
      x, dd, b0, b1, b2, b3, b4, b5, b6, b7, bsig, b8, b9, b10, b11, b12, brgb,
      (float*)d_out);
}

// Round 18
// 316.713 us; speedup vs baseline: 3.1722x; 3.1722x over previous
//
#include <hip/hip_runtime.h>
#include <hip/hip_bf16.h>

#define NB 262144
#define RTILE 64

typedef __bf16 bf16x8 __attribute__((ext_vector_type(8)));
typedef float f32x4 __attribute__((ext_vector_type(4)));

// ---- packed bf16 weight buffer ----
// MFMA layers fragment-ordered: fragment (colTile,ks) at
//   off + ((colTile*KSTRIDE + ks)*64 + lane)*8
// lane's elems: W[col=colTile*16+(lane&15)][k=ks*32+(lane>>4)*8+e].
// Wsig/Wrgb plain row-major.
#define OFF_W0   0        // [256][64]   (K 63->64)
#define OFF_W1   16384    // [256][256]
#define OFF_W2   81920
#define OFF_W3   147456
#define OFF_W4   212992
#define OFF_W5   278528   // [256][320]  (K 319->320; ks 8,9 = x)
#define OFF_W6   360448
#define OFF_W7   425984
#define OFF_WSIG 491520   // [1][256] plain
#define OFF_W8   491776   // [256][256]
#define OFF_W9   557312   // [128][288]  (K 283->288; ks 8 = d)
#define OFF_W10  594176   // [128][128]
#define OFF_W11  610560
#define OFF_W12  626944
#define OFF_WRGB 643328   // [3][128] plain
#define WTOTAL   643712

__device__ __align__(16) unsigned short g_w[WTOTAL];

__device__ __forceinline__ unsigned short f2bfu(float f) {
  __bf16 h = (__bf16)f;
  return __builtin_bit_cast(unsigned short, h);
}
__device__ __forceinline__ float bfu2f(unsigned short u) {
  return (float)__builtin_bit_cast(__bf16, u);
}

// lgkm-only barrier: orders LDS producer->consumer without draining vmcnt
// (cross-layer weight prefetch stays in flight). sched_barrier fences
// compiler motion (rule #18).
#define LAYER_BARRIER() do { \
  asm volatile("s_waitcnt lgkmcnt(0)\n\ts_barrier" ::: "memory"); \
  __builtin_amdgcn_sched_barrier(0); \
} while (0)

__global__ void prep_kernel(const float* W0, const float* W1, const float* W2,
                            const float* W3, const float* W4, const float* W5,
                            const float* W6, const float* W7, const float* Wsig,
                            const float* W8, const float* W9, const float* W10,
                            const float* W11, const float* W12, const float* Wrgb) {
  const float* srcs[15] = {W0,W1,W2,W3,W4,W5,W6,W7,Wsig,W8,W9,W10,W11,W12,Wrgb};
  const int dsto[16] = {OFF_W0,OFF_W1,OFF_W2,OFF_W3,OFF_W4,OFF_W5,OFF_W6,OFF_W7,
                        OFF_WSIG,OFF_W8,OFF_W9,OFF_W10,OFF_W11,OFF_W12,OFF_WRGB,WTOTAL};
  const int kpad[15] = {64,256,256,256,256,320,256,256,256,256,288,128,128,128,128};
  const int ksrc[15] = {63,256,256,256,256,319,256,256,256,256,283,128,128,128,128};
  int idx = blockIdx.x * blockDim.x + threadIdx.x;
  if (idx >= WTOTAL) return;
  int r = 0;
  for (int i = 1; i < 15; ++i) if (idx >= dsto[i]) r = i;
  int local = idx - dsto[r];
  float v;
  if (r == 8 || r == 14) {             // head weights: plain row-major
    int o = local / kpad[r];
    int k = local - o * kpad[r];
    v = (k < ksrc[r]) ? srcs[r][o * ksrc[r] + k] : 0.0f;
  } else {                             // MFMA layers: fragment-ordered
    const int KS = kpad[r] >> 5;
    int frag = local >> 9;
    int within = local & 511;
    int lane = within >> 3;
    int e = within & 7;
    int colTile = frag / KS;
    int ks = frag - colTile * KS;
    int col = colTile * 16 + (lane & 15);
    int k = ks * 32 + (lane >> 4) * 8 + e;
    v = (k < ksrc[r]) ? srcs[r][col * ksrc[r] + k] : 0.0f;
  }
  g_w[idx] = f2bfu(v);
}

// ---- fused MLP ----
// r18: 512-thread blocks (8 waves), NT=2 column stripes (32 cols/wave).
// launch_bounds(512,4) -> 2 blocks/CU = 4 waves/SIMD (vs 3), per-wave issue
// halved, and waves on a SIMD come from independently-phased blocks (the
// r16 counters showed MFMA+VALU ~= serial sum -> phase overlap is the gap).
// Register pressure drops (acc 32, b 8) so the 128-VGPR budget is safe.
// Everything else = r16: fragment-ordered LDS, copy-free parity pipeline,
// bias-folded acc, cross-layer weight prefetch, lgkm-only barriers,
// swapped-operand 16x16x32 MFMA.
template<int KSTRIDE, int NT>
__device__ __forceinline__ void prefetch_b0(
    const unsigned short* Wp, bf16x8 (&b)[2][2], int lane, int wid)
{
  const unsigned short* wb = Wp + (size_t)(wid * NT) * KSTRIDE * 512 + lane * 8;
#pragma unroll
  for (int ct = 0; ct < NT; ++ct)
    b[0][ct] = *(const bf16x8*)&wb[(size_t)(ct * KSTRIDE) * 512];
}

template<int KS1, int KSA1, int KS2, int KSA2, int KSTRIDE, int NT>
__device__ __forceinline__ void gemm_compute(
    const unsigned short* A1,
    const unsigned short* A2,
    const unsigned short* Wp,
    const float* bias,
    bf16x8 (&b)[2][2],                  // b[0][0..NT-1] preloaded by caller
    f32x4 (&acc)[4][NT],
    int lane, int wid)
{
  constexpr int KS = KS1 + KS2;
  const int l4 = lane >> 4;
  const unsigned short* wb = Wp + (size_t)(wid * NT) * KSTRIDE * 512 + lane * 8;
  const unsigned short* a1 = A1 + lane * 8;
  const unsigned short* a2 = A2 ? (A2 + lane * 8) : nullptr;

  // bias-folded accumulator init
#pragma unroll
  for (int ct = 0; ct < NT; ++ct) {
    const f32x4 bv = *(const f32x4*)&bias[wid * (NT * 16) + ct * 16 + l4 * 4];
#pragma unroll
    for (int rt = 0; rt < 4; ++rt)
      acc[rt][ct] = bv;
  }

  bf16x8 a[2][4];
#pragma unroll
  for (int rt = 0; rt < 4; ++rt)
    a[0][rt] = *(const bf16x8*)&a1[(rt * KSA1) * 512];

#pragma unroll
  for (int kk = 0; kk < KS; ++kk) {
    if (kk + 1 < KS) {
#pragma unroll
      for (int ct = 0; ct < NT; ++ct)
        b[(kk + 1) & 1][ct] = *(const bf16x8*)&wb[(size_t)(ct * KSTRIDE + kk + 1) * 512];
#pragma unroll
      for (int rt = 0; rt < 4; ++rt) {
        if (kk + 1 < KS1)
          a[(kk + 1) & 1][rt] = *(const bf16x8*)&a1[(rt * KSA1 + kk + 1) * 512];
        else
          a[(kk + 1) & 1][rt] = *(const bf16x8*)&a2[(rt * KSA2 + (kk + 1 - KS1)) * 512];
      }
    }
    __builtin_amdgcn_s_setprio(1);
#pragma unroll
    for (int rt = 0; rt < 4; ++rt)
#pragma unroll
      for (int ct = 0; ct < NT; ++ct)
        acc[rt][ct] = __builtin_amdgcn_mfma_f32_16x16x32_bf16(
            b[kk & 1][ct], a[kk & 1][rt], acc[rt][ct], 0, 0, 0);
    __builtin_amdgcn_s_setprio(0);
  }
}

// Store acc (already biased) into fragment-ordered H (KSH=8 stride).
template<int NT, bool RELU>
__device__ __forceinline__ void store_acc(
    const f32x4 (&acc)[4][NT],
    unsigned short* Out, int lane, int wid)
{
  const int l15 = lane & 15;
  const int l4  = lane >> 4;
  const int colbase = wid * (NT * 16);
#pragma unroll
  for (int ct = 0; ct < NT; ++ct) {
    const int c0 = colbase + ct * 16 + l4 * 4;
    const int f  = c0 >> 5;
    const int li = l15 + 16 * ((c0 >> 3) & 3);
    const int e0 = c0 & 7;
#pragma unroll
    for (int rt = 0; rt < 4; ++rt) {
      float v0 = acc[rt][ct][0];
      float v1 = acc[rt][ct][1];
      float v2 = acc[rt][ct][2];
      float v3 = acc[rt][ct][3];
      if (RELU) {
        v0 = fmaxf(v0, 0.f); v1 = fmaxf(v1, 0.f);
        v2 = fmaxf(v2, 0.f); v3 = fmaxf(v3, 0.f);
      }
      uint2 u;
      u.x = (unsigned)f2bfu(v0) | ((unsigned)f2bfu(v1) << 16);
      u.y = (unsigned)f2bfu(v2) | ((unsigned)f2bfu(v3) << 16);
      *(uint2*)&Out[(rt * 8 + f) * 512 + li * 8 + e0] = u;
    }
  }
}

// L7 store + fused sigma partials (h7 . Wsig); NT=2, 8 waves.
__device__ __forceinline__ void store_acc_sigma(
    const f32x4 (&acc)[4][2],
    unsigned short* Out, float* Sb, int lane, int wid)
{
  const int l15 = lane & 15;
  const int l4  = lane >> 4;
  const int colbase = wid * 32;
  float ps[4] = {0.f, 0.f, 0.f, 0.f};
#pragma unroll
  for (int ct = 0; ct < 2; ++ct) {
    const int c0 = colbase + ct * 16 + l4 * 4;
    const int f  = c0 >> 5;
    const int li = l15 + 16 * ((c0 >> 3) & 3);
    const int e0 = c0 & 7;
    const ushort4 wu = *(const ushort4*)&g_w[OFF_WSIG + c0];
    const float w0 = bfu2f(wu.x), w1 = bfu2f(wu.y), w2 = bfu2f(wu.z), w3 = bfu2f(wu.w);
#pragma unroll
    for (int rt = 0; rt < 4; ++rt) {
      float v0 = fmaxf(acc[rt][ct][0], 0.f);
      float v1 = fmaxf(acc[rt][ct][1], 0.f);
      float v2 = fmaxf(acc[rt][ct][2], 0.f);
      float v3 = fmaxf(acc[rt][ct][3], 0.f);
      uint2 u;
      u.x = (unsigned)f2bfu(v0) | ((unsigned)f2bfu(v1) << 16);
      u.y = (unsigned)f2bfu(v2) | ((unsigned)f2bfu(v3) << 16);
      *(uint2*)&Out[(rt * 8 + f) * 512 + li * 8 + e0] = u;
      ps[rt] += bfu2f(f2bfu(v0)) * w0 + bfu2f(f2bfu(v1)) * w1
              + bfu2f(f2bfu(v2)) * w2 + bfu2f(f2bfu(v3)) * w3;
    }
  }
#pragma unroll
  for (int rt = 0; rt < 4; ++rt) {
    ps[rt] += __shfl_xor(ps[rt], 16);
    ps[rt] += __shfl_xor(ps[rt], 32);
  }
  if (l4 == 0) {
#pragma unroll
    for (int rt = 0; rt < 4; ++rt)
      Sb[wid * 64 + rt * 16 + l15] = ps[rt];
  }
}

// L12 epilogue: rgb partials from acc (NT=1, 16 cols/wave).
__device__ __forceinline__ void rgb_partial(
    const f32x4 (&acc)[4][1],
    float* Rb, int lane, int wid)
{
  const int l15 = lane & 15;
  const int l4  = lane >> 4;
  const int c0 = wid * 16 + l4 * 4;
  float pr[4][3] = {};
  float wf[3][4];
#pragma unroll
  for (int ch = 0; ch < 3; ++ch) {
    const ushort4 wu = *(const ushort4*)&g_w[OFF_WRGB + ch * 128 + c0];
    wf[ch][0] = bfu2f(wu.x); wf[ch][1] = bfu2f(wu.y);
    wf[ch][2] = bfu2f(wu.z); wf[ch][3] = bfu2f(wu.w);
  }
#pragma unroll
  for (int rt = 0; rt < 4; ++rt) {
    float v0 = fmaxf(acc[rt][0][0], 0.f);
    float v1 = fmaxf(acc[rt][0][1], 0.f);
    float v2 = fmaxf(acc[rt][0][2], 0.f);
    float v3 = fmaxf(acc[rt][0][3], 0.f);
#pragma unroll
    for (int ch = 0; ch < 3; ++ch)
      pr[rt][ch] += v0 * wf[ch][0] + v1 * wf[ch][1] + v2 * wf[ch][2] + v3 * wf[ch][3];
  }
#pragma unroll
  for (int rt = 0; rt < 4; ++rt)
#pragma unroll
    for (int ch = 0; ch < 3; ++ch) {
      pr[rt][ch] += __shfl_xor(pr[rt][ch], 16);
      pr[rt][ch] += __shfl_xor(pr[rt][ch], 32);
    }
  if (l4 == 0) {
#pragma unroll
    for (int rt = 0; rt < 4; ++rt)
#pragma unroll
      for (int ch = 0; ch < 3; ++ch)
        Rb[((wid * 4 + rt) * 3 + ch) * 16 + l15] = pr[rt][ch];
  }
}

__launch_bounds__(512, 4)
__global__ void nerf_main(const float* __restrict__ x, const float* __restrict__ d,
    const float* b0, const float* b1, const float* b2, const float* b3,
    const float* b4, const float* b5, const float* b6, const float* b7,
    const float* bsig, const float* b8, const float* b9, const float* b10,
    const float* b11, const float* b12, const float* brgb,
    float* __restrict__ out)
{
  __shared__ __align__(16) unsigned short H[64 * 256];   // 32768 B, frag-ordered KSH=8
  __shared__ __align__(16) unsigned short Xb[64 * 64];   // 8192 B, KSX=2
  __shared__ __align__(16) unsigned short Db[64 * 32];   // 4096 B, KSD=1
  __shared__ float Sb[512];                // 2048 B sigma partials (8 waves x 64 rows)
  __shared__ float Rb[1536];               // 6144 B rgb partials
  // total 53248 B -> 2 blocks/CU at launch_bounds(512,4)

  const int tid = threadIdx.x;
  const int lane = tid & 63;
  const int wid = tid >> 6;               // 0..7
  const int rowbase = blockIdx.x * RTILE;

  bf16x8 bb[2][2];
  f32x4 acc4[4][2];
  f32x4 acc1[4][1];

  // prefetch W0 kk=0 frags first -- overlaps the staging phase
  prefetch_b0<2,2>(g_w + OFF_W0, bb, lane, wid);

  // ---- stage x and d tiles (fp32 -> bf16, fragment-ordered writes) ----
  {
    const int r = tid >> 3;      // 0..63
    const int sub = tid & 7;
    const int rt = r >> 4;
    const int rl = r & 15;
    const float* xr = x + (size_t)(rowbase + r) * 63;
    for (int j = 0; j < 8; ++j) {
      const int c = sub + j * 8;        // 0..63
      const unsigned short v = (c < 63) ? f2bfu(xr[c]) : (unsigned short)0;
      Xb[(rt * 2 + (c >> 5)) * 512 + (rl + 16 * ((c >> 3) & 3)) * 8 + (c & 7)] = v;
    }
    const float* dr = d + (size_t)(rowbase + r) * 27;
    for (int j = 0; j < 4; ++j) {
      const int c = sub + j * 8;        // 0..31
      const unsigned short v = (c < 27) ? f2bfu(dr[c]) : (unsigned short)0;
      Db[rt * 512 + (rl + 16 * ((c >> 3) & 3)) * 8 + (c & 7)] = v;
    }
  }
  LAYER_BARRIER();

  // L0: reads Xb only -> write H directly (first writer)
  gemm_compute<2,2,0,0,2,2>(Xb, nullptr, g_w + OFF_W0, b0, bb, acc4, lane, wid);
  prefetch_b0<8,2>(g_w + OFF_W1, bb, lane, wid);
  store_acc<2,true>(acc4, H, lane, wid);
  LAYER_BARRIER();

#define BIG_LAYER(OFFW, BIAS, PF) \
  gemm_compute<8,8,0,0,8,2>(H, nullptr, g_w + OFFW, BIAS, bb, acc4, lane, wid); \
  PF; \
  LAYER_BARRIER(); \
  store_acc<2,true>(acc4, H, lane, wid); \
  LAYER_BARRIER();

  BIG_LAYER(OFF_W1, b1, (prefetch_b0<8,2>(g_w + OFF_W2, bb, lane, wid)))
  BIG_LAYER(OFF_W2, b2, (prefetch_b0<8,2>(g_w + OFF_W3, bb, lane, wid)))
  BIG_LAYER(OFF_W3, b3, (prefetch_b0<8,2>(g_w + OFF_W4, bb, lane, wid)))
  BIG_LAYER(OFF_W4, b4, (prefetch_b0<10,2>(g_w + OFF_W5, bb, lane, wid)))

  // L5: concat [h(256) | x(63)+pad] -> K=320
  gemm_compute<8,8,2,2,10,2>(H, Xb, g_w + OFF_W5, b5, bb, acc4, lane, wid);
  prefetch_b0<8,2>(g_w + OFF_W6, bb, lane, wid);
  LAYER_BARRIER();
  store_acc<2,true>(acc4, H, lane, wid);
  LAYER_BARRIER();

  BIG_LAYER(OFF_W6, b6, (prefetch_b0<8,2>(g_w + OFF_W7, bb, lane, wid)))

  // L7 + fused sigma partials
  gemm_compute<8,8,0,0,8,2>(H, nullptr, g_w + OFF_W7, b7, bb, acc4, lane, wid);
  prefetch_b0<8,2>(g_w + OFF_W8, bb, lane, wid);
  LAYER_BARRIER();
  store_acc_sigma(acc4, H, Sb, lane, wid);
  LAYER_BARRIER();

  // finish sigma: 64 threads, Sb stable from here on
  if (tid < 64) {
    float s = bsig[0];
#pragma unroll
    for (int w = 0; w < 8; ++w)
      s += Sb[w * 64 + tid];
    float sp = (s > 0.f) ? (s + log1pf(expf(-s))) : log1pf(expf(s));
    out[3 * NB + rowbase + tid] = sp;
  }

  // L8 (bottleneck, no relu)
  gemm_compute<8,8,0,0,8,2>(H, nullptr, g_w + OFF_W8, b8, bb, acc4, lane, wid);
  prefetch_b0<9,1>(g_w + OFF_W9, bb, lane, wid);
  LAYER_BARRIER();
  store_acc<2,false>(acc4, H, lane, wid);
  LAYER_BARRIER();

  // L9: concat [h8(256) | d(27)+pad] -> K=288, N=128 (NT=1: 16 cols/wave)
  gemm_compute<8,8,1,1,9,1>(H, Db, g_w + OFF_W9, b9, bb, acc1, lane, wid);
  prefetch_b0<4,1>(g_w + OFF_W10, bb, lane, wid);
  LAYER_BARRIER();
  store_acc<1,true>(acc1, H, lane, wid);
  LAYER_BARRIER();

#define SMALL_LAYER(OFFW, BIAS, PF) \
  gemm_compute<4,8,0,0,4,1>(H, nullptr, g_w + OFFW, BIAS, bb, acc1, lane, wid); \
  PF; \
  LAYER_BARRIER(); \
  store_acc<1,true>(acc1, H, lane, wid); \
  LAYER_BARRIER();

  SMALL_LAYER(OFF_W10, b10, (prefetch_b0<4,1>(g_w + OFF_W11, bb, lane, wid)))
  SMALL_LAYER(OFF_W11, b11, (prefetch_b0<4,1>(g_w + OFF_W12, bb, lane, wid)))

  // L12 + fused rgb head: h12 never touches LDS
  gemm_compute<4,8,0,0,4,1>(H, nullptr, g_w + OFF_W12, b12, bb, acc1, lane, wid);
  rgb_partial(acc1, Rb, lane, wid);
  LAYER_BARRIER();

  if (tid < 192) {
    const int r = tid / 3;
    const int ch = tid - r * 3;
    const int rt = r >> 4;
    const int l15r = r & 15;
    float s = brgb[ch];
#pragma unroll
    for (int w = 0; w < 8; ++w)
      s += Rb[((w * 4 + rt) * 3 + ch) * 16 + l15r];
    float val = 1.f / (1.f + expf(-s));
    out[(size_t)(rowbase + r) * 3 + ch] = val;
  }
}

extern "C" void kernel_launch(void* const* d_in, const int* in_sizes, int n_in,
                              void* d_out, int out_size, void* d_ws, size_t ws_size,
                              hipStream_t stream) {
  const float* x    = (const float*)d_in[0];
  const float* dd   = (const float*)d_in[1];
  const float* W0   = (const float*)d_in[2];
  const float* b0   = (const float*)d_in[3];
  const float* W1   = (const float*)d_in[4];
  const float* b1   = (const float*)d_in[5];
  const float* W2   = (const float*)d_in[6];
  const float* b2   = (const float*)d_in[7];
  const float* W3   = (const float*)d_in[8];
  const float* b3   = (const float*)d_in[9];
  const float* W4   = (const float*)d_in[10];
  const float* b4   = (const float*)d_in[11];
  const float* W5   = (const float*)d_in[12];
  const float* b5   = (const float*)d_in[13];
  const float* W6   = (const float*)d_in[14];
  const float* b6   = (const float*)d_in[15];
  const float* W7   = (const float*)d_in[16];
  const float* b7   = (const float*)d_in[17];
  const float* Wsig = (const float*)d_in[18];
  const float* bsig = (const float*)d_in[19];
  const float* W8   = (const float*)d_in[20];
  const float* b8   = (const float*)d_in[21];
  const float* W9   = (const float*)d_in[22];
  const float* b9   = (const float*)d_in[23];
  const float* W10  = (const float*)d_in[24];
  const float* b10  = (const float*)d_in[25];
  const float* W11  = (const float*)d_in[26];
  const float* b11  = (const float*)d_in[27];
  const float* W12  = (const float*)d_in[28];
  const float* b12  = (const float*)d_in[29];
  const float* Wrgb = (const float*)d_in[30];
  const float* brgb = (const float*)d_in[31];

  prep_kernel<<<(WTOTAL + 255) / 256, 256, 0, stream>>>(
      W0, W1, W2, W3, W4, W5, W6, W7, Wsig, W8, W9, W10, W11, W12, Wrgb);

  nerf_main<<<NB / RTILE, 512, 0, stream>>>(
      x, dd, b0, b1, b2, b3, b4, b5, b6, b7, bsig, b8, b9, b10, b11, b12, brgb,
      (float*)d_out);
}

// Round 19
// 313.469 us; speedup vs baseline: 3.2050x; 1.0103x over previous
//
#include <hip/hip_runtime.h>
#include <hip/hip_bf16.h>

#define NB 262144
#define RTILE 64

typedef __bf16 bf16x8 __attribute__((ext_vector_type(8)));
typedef float f32x4 __attribute__((ext_vector_type(4)));

// ---- packed bf16 weight buffer ----
// MFMA layers fragment-ordered: fragment (colTile,ks) at
//   off + ((colTile*KSTRIDE + ks)*64 + lane)*8
// lane's elems: W[col=colTile*16+(lane&15)][k=ks*32+(lane>>4)*8+e].
// Wsig/Wrgb plain row-major.
#define OFF_W0   0        // [256][64]   (K 63->64)
#define OFF_W1   16384    // [256][256]
#define OFF_W2   81920
#define OFF_W3   147456
#define OFF_W4   212992
#define OFF_W5   278528   // [256][320]  (K 319->320; ks 8,9 = x)
#define OFF_W6   360448
#define OFF_W7   425984
#define OFF_WSIG 491520   // [1][256] plain
#define OFF_W8   491776   // [256][256]
#define OFF_W9   557312   // [128][288]  (K 283->288; ks 8 = d)
#define OFF_W10  594176   // [128][128]
#define OFF_W11  610560
#define OFF_W12  626944
#define OFF_WRGB 643328   // [3][128] plain
#define WTOTAL   643712

__device__ __align__(16) unsigned short g_w[WTOTAL];

__device__ __forceinline__ unsigned short f2bfu(float f) {
  __bf16 h = (__bf16)f;
  return __builtin_bit_cast(unsigned short, h);
}
__device__ __forceinline__ float bfu2f(unsigned short u) {
  return (float)__builtin_bit_cast(__bf16, u);
}

// lgkm-only barrier: orders LDS producer->consumer without draining vmcnt
// (cross-layer weight prefetch stays in flight). sched_barrier fences
// compiler motion (rule #18).
#define LAYER_BARRIER() do { \
  asm volatile("s_waitcnt lgkmcnt(0)\n\ts_barrier" ::: "memory"); \
  __builtin_amdgcn_sched_barrier(0); \
} while (0)

__global__ void prep_kernel(const float* W0, const float* W1, const float* W2,
                            const float* W3, const float* W4, const float* W5,
                            const float* W6, const float* W7, const float* Wsig,
                            const float* W8, const float* W9, const float* W10,
                            const float* W11, const float* W12, const float* Wrgb) {
  const float* srcs[15] = {W0,W1,W2,W3,W4,W5,W6,W7,Wsig,W8,W9,W10,W11,W12,Wrgb};
  const int dsto[16] = {OFF_W0,OFF_W1,OFF_W2,OFF_W3,OFF_W4,OFF_W5,OFF_W6,OFF_W7,
                        OFF_WSIG,OFF_W8,OFF_W9,OFF_W10,OFF_W11,OFF_W12,OFF_WRGB,WTOTAL};
  const int kpad[15] = {64,256,256,256,256,320,256,256,256,256,288,128,128,128,128};
  const int ksrc[15] = {63,256,256,256,256,319,256,256,256,256,283,128,128,128,128};
  int idx = blockIdx.x * blockDim.x + threadIdx.x;
  if (idx >= WTOTAL) return;
  int r = 0;
  for (int i = 1; i < 15; ++i) if (idx >= dsto[i]) r = i;
  int local = idx - dsto[r];
  float v;
  if (r == 8 || r == 14) {             // head weights: plain row-major
    int o = local / kpad[r];
    int k = local - o * kpad[r];
    v = (k < ksrc[r]) ? srcs[r][o * ksrc[r] + k] : 0.0f;
  } else {                             // MFMA layers: fragment-ordered
    const int KS = kpad[r] >> 5;
    int frag = local >> 9;
    int within = local & 511;
    int lane = within >> 3;
    int e = within & 7;
    int colTile = frag / KS;
    int ks = frag - colTile * KS;
    int col = colTile * 16 + (lane & 15);
    int k = ks * 32 + (lane >> 4) * 8 + e;
    v = (k < ksrc[r]) ? srcs[r][col * ksrc[r] + k] : 0.0f;
  }
  g_w[idx] = f2bfu(v);
}

// ---- fused MLP ----
// r19: H PING-PONG (Ha/Hb) -> ONE barrier per layer instead of two.
// The pre-store barrier in r16/r18 was a WAR guard (store overwrote the H
// being read). With ping-pong, a wave reaches the barrier only after its
// reads of the IN buffer are done and its writes to the OUT buffer are
// stored -> next layer may read OUT and overwrite IN safely. 13 barriers
// vs 26. 512-thr blocks (8 waves, r18 shape): 2 blocks/CU at 77824 B LDS,
// 4 waves/SIMD. Sb/Rb live in the dead-after-L5 Xb region.
// Everything else = r18: fragment-ordered LDS, copy-free parity K-pipeline,
// bias-folded acc, cross-layer weight prefetch, lgkm-only barriers,
// swapped-operand 16x16x32 MFMA.
template<int KSTRIDE, int NT>
__device__ __forceinline__ void prefetch_b0(
    const unsigned short* Wp, bf16x8 (&b)[2][2], int lane, int wid)
{
  const unsigned short* wb = Wp + (size_t)(wid * NT) * KSTRIDE * 512 + lane * 8;
#pragma unroll
  for (int ct = 0; ct < NT; ++ct)
    b[0][ct] = *(const bf16x8*)&wb[(size_t)(ct * KSTRIDE) * 512];
}

template<int KS1, int KSA1, int KS2, int KSA2, int KSTRIDE, int NT>
__device__ __forceinline__ void gemm_compute(
    const unsigned short* A1,
    const unsigned short* A2,
    const unsigned short* Wp,
    const float* bias,
    bf16x8 (&b)[2][2],                  // b[0][0..NT-1] preloaded by caller
    f32x4 (&acc)[4][NT],
    int lane, int wid)
{
  constexpr int KS = KS1 + KS2;
  const int l4 = lane >> 4;
  const unsigned short* wb = Wp + (size_t)(wid * NT) * KSTRIDE * 512 + lane * 8;
  const unsigned short* a1 = A1 + lane * 8;
  const unsigned short* a2 = A2 ? (A2 + lane * 8) : nullptr;

  // bias-folded accumulator init
#pragma unroll
  for (int ct = 0; ct < NT; ++ct) {
    const f32x4 bv = *(const f32x4*)&bias[wid * (NT * 16) + ct * 16 + l4 * 4];
#pragma unroll
    for (int rt = 0; rt < 4; ++rt)
      acc[rt][ct] = bv;
  }

  bf16x8 a[2][4];
#pragma unroll
  for (int rt = 0; rt < 4; ++rt)
    a[0][rt] = *(const bf16x8*)&a1[(rt * KSA1) * 512];

#pragma unroll
  for (int kk = 0; kk < KS; ++kk) {
    if (kk + 1 < KS) {
#pragma unroll
      for (int ct = 0; ct < NT; ++ct)
        b[(kk + 1) & 1][ct] = *(const bf16x8*)&wb[(size_t)(ct * KSTRIDE + kk + 1) * 512];
#pragma unroll
      for (int rt = 0; rt < 4; ++rt) {
        if (kk + 1 < KS1)
          a[(kk + 1) & 1][rt] = *(const bf16x8*)&a1[(rt * KSA1 + kk + 1) * 512];
        else
          a[(kk + 1) & 1][rt] = *(const bf16x8*)&a2[(rt * KSA2 + (kk + 1 - KS1)) * 512];
      }
    }
    __builtin_amdgcn_s_setprio(1);
#pragma unroll
    for (int rt = 0; rt < 4; ++rt)
#pragma unroll
      for (int ct = 0; ct < NT; ++ct)
        acc[rt][ct] = __builtin_amdgcn_mfma_f32_16x16x32_bf16(
            b[kk & 1][ct], a[kk & 1][rt], acc[rt][ct], 0, 0, 0);
    __builtin_amdgcn_s_setprio(0);
  }
}

// Store acc (already biased) into fragment-ordered H (KSH=8 stride).
template<int NT, bool RELU>
__device__ __forceinline__ void store_acc(
    const f32x4 (&acc)[4][NT],
    unsigned short* Out, int lane, int wid)
{
  const int l15 = lane & 15;
  const int l4  = lane >> 4;
  const int colbase = wid * (NT * 16);
#pragma unroll
  for (int ct = 0; ct < NT; ++ct) {
    const int c0 = colbase + ct * 16 + l4 * 4;
    const int f  = c0 >> 5;
    const int li = l15 + 16 * ((c0 >> 3) & 3);
    const int e0 = c0 & 7;
#pragma unroll
    for (int rt = 0; rt < 4; ++rt) {
      float v0 = acc[rt][ct][0];
      float v1 = acc[rt][ct][1];
      float v2 = acc[rt][ct][2];
      float v3 = acc[rt][ct][3];
      if (RELU) {
        v0 = fmaxf(v0, 0.f); v1 = fmaxf(v1, 0.f);
        v2 = fmaxf(v2, 0.f); v3 = fmaxf(v3, 0.f);
      }
      uint2 u;
      u.x = (unsigned)f2bfu(v0) | ((unsigned)f2bfu(v1) << 16);
      u.y = (unsigned)f2bfu(v2) | ((unsigned)f2bfu(v3) << 16);
      *(uint2*)&Out[(rt * 8 + f) * 512 + li * 8 + e0] = u;
    }
  }
}

// L7 store + fused sigma partials (h7 . Wsig); NT=2, 8 waves.
__device__ __forceinline__ void store_acc_sigma(
    const f32x4 (&acc)[4][2],
    unsigned short* Out, float* Sb, int lane, int wid)
{
  const int l15 = lane & 15;
  const int l4  = lane >> 4;
  const int colbase = wid * 32;
  float ps[4] = {0.f, 0.f, 0.f, 0.f};
#pragma unroll
  for (int ct = 0; ct < 2; ++ct) {
    const int c0 = colbase + ct * 16 + l4 * 4;
    const int f  = c0 >> 5;
    const int li = l15 + 16 * ((c0 >> 3) & 3);
    const int e0 = c0 & 7;
    const ushort4 wu = *(const ushort4*)&g_w[OFF_WSIG + c0];
    const float w0 = bfu2f(wu.x), w1 = bfu2f(wu.y), w2 = bfu2f(wu.z), w3 = bfu2f(wu.w);
#pragma unroll
    for (int rt = 0; rt < 4; ++rt) {
      float v0 = fmaxf(acc[rt][ct][0], 0.f);
      float v1 = fmaxf(acc[rt][ct][1], 0.f);
      float v2 = fmaxf(acc[rt][ct][2], 0.f);
      float v3 = fmaxf(acc[rt][ct][3], 0.f);
      uint2 u;
      u.x = (unsigned)f2bfu(v0) | ((unsigned)f2bfu(v1) << 16);
      u.y = (unsigned)f2bfu(v2) | ((unsigned)f2bfu(v3) << 16);
      *(uint2*)&Out[(rt * 8 + f) * 512 + li * 8 + e0] = u;
      ps[rt] += bfu2f(f2bfu(v0)) * w0 + bfu2f(f2bfu(v1)) * w1
              + bfu2f(f2bfu(v2)) * w2 + bfu2f(f2bfu(v3)) * w3;
    }
  }
#pragma unroll
  for (int rt = 0; rt < 4; ++rt) {
    ps[rt] += __shfl_xor(ps[rt], 16);
    ps[rt] += __shfl_xor(ps[rt], 32);
  }
  if (l4 == 0) {
#pragma unroll
    for (int rt = 0; rt < 4; ++rt)
      Sb[wid * 64 + rt * 16 + l15] = ps[rt];
  }
}

// L12 epilogue: rgb partials from acc (NT=1, 16 cols/wave).
__device__ __forceinline__ void rgb_partial(
    const f32x4 (&acc)[4][1],
    float* Rb, int lane, int wid)
{
  const int l15 = lane & 15;
  const int l4  = lane >> 4;
  const int c0 = wid * 16 + l4 * 4;
  float pr[4][3] = {};
  float wf[3][4];
#pragma unroll
  for (int ch = 0; ch < 3; ++ch) {
    const ushort4 wu = *(const ushort4*)&g_w[OFF_WRGB + ch * 128 + c0];
    wf[ch][0] = bfu2f(wu.x); wf[ch][1] = bfu2f(wu.y);
    wf[ch][2] = bfu2f(wu.z); wf[ch][3] = bfu2f(wu.w);
  }
#pragma unroll
  for (int rt = 0; rt < 4; ++rt) {
    float v0 = fmaxf(acc[rt][0][0], 0.f);
    float v1 = fmaxf(acc[rt][0][1], 0.f);
    float v2 = fmaxf(acc[rt][0][2], 0.f);
    float v3 = fmaxf(acc[rt][0][3], 0.f);
#pragma unroll
    for (int ch = 0; ch < 3; ++ch)
      pr[rt][ch] += v0 * wf[ch][0] + v1 * wf[ch][1] + v2 * wf[ch][2] + v3 * wf[ch][3];
  }
#pragma unroll
  for (int rt = 0; rt < 4; ++rt)
#pragma unroll
    for (int ch = 0; ch < 3; ++ch) {
      pr[rt][ch] += __shfl_xor(pr[rt][ch], 16);
      pr[rt][ch] += __shfl_xor(pr[rt][ch], 32);
    }
  if (l4 == 0) {
#pragma unroll
    for (int rt = 0; rt < 4; ++rt)
#pragma unroll
      for (int ch = 0; ch < 3; ++ch)
        Rb[((wid * 4 + rt) * 3 + ch) * 16 + l15] = pr[rt][ch];
  }
}

__launch_bounds__(512, 4)
__global__ void nerf_main(const float* __restrict__ x, const float* __restrict__ d,
    const float* b0, const float* b1, const float* b2, const float* b3,
    const float* b4, const float* b5, const float* b6, const float* b7,
    const float* bsig, const float* b8, const float* b9, const float* b10,
    const float* b11, const float* b12, const float* brgb,
    float* __restrict__ out)
{
  __shared__ __align__(16) unsigned short Ha[64 * 256];  // 32768 B, frag-ordered KSH=8
  __shared__ __align__(16) unsigned short Hb[64 * 256];  // 32768 B ping-pong partner
  __shared__ __align__(16) unsigned short Xb[64 * 64];   // 8192 B, KSX=2; Sb/Rb after L5
  __shared__ __align__(16) unsigned short Db[64 * 32];   // 4096 B, KSD=1
  float* Sb = (float*)Xb;                  // bytes 0..2047 of Xb (written L7)
  float* Rb = (float*)(Xb + 1024);         // bytes 2048..8191 (written L12)
  // total 77824 B -> 2 blocks/CU at launch_bounds(512,4)

  const int tid = threadIdx.x;
  const int lane = tid & 63;
  const int wid = tid >> 6;               // 0..7
  const int rowbase = blockIdx.x * RTILE;

  bf16x8 bb[2][2];
  f32x4 acc4[4][2];
  f32x4 acc1[4][1];

  // prefetch W0 kk=0 frags first -- overlaps the staging phase
  prefetch_b0<2,2>(g_w + OFF_W0, bb, lane, wid);

  // ---- stage x and d tiles (fp32 -> bf16, fragment-ordered writes) ----
  {
    const int r = tid >> 3;      // 0..63
    const int sub = tid & 7;
    const int rt = r >> 4;
    const int rl = r & 15;
    const float* xr = x + (size_t)(rowbase + r) * 63;
    for (int j = 0; j < 8; ++j) {
      const int c = sub + j * 8;        // 0..63
      const unsigned short v = (c < 63) ? f2bfu(xr[c]) : (unsigned short)0;
      Xb[(rt * 2 + (c >> 5)) * 512 + (rl + 16 * ((c >> 3) & 3)) * 8 + (c & 7)] = v;
    }
    const float* dr = d + (size_t)(rowbase + r) * 27;
    for (int j = 0; j < 4; ++j) {
      const int c = sub + j * 8;        // 0..31
      const unsigned short v = (c < 27) ? f2bfu(dr[c]) : (unsigned short)0;
      Db[rt * 512 + (rl + 16 * ((c >> 3) & 3)) * 8 + (c & 7)] = v;
    }
  }
  LAYER_BARRIER();

  // L0: Xb -> Ha (single barrier per layer from here on: ping-pong makes
  // the post-gemm WAR barrier unnecessary)
  gemm_compute<2,2,0,0,2,2>(Xb, nullptr, g_w + OFF_W0, b0, bb, acc4, lane, wid);
  prefetch_b0<8,2>(g_w + OFF_W1, bb, lane, wid);
  store_acc<2,true>(acc4, Ha, lane, wid);
  LAYER_BARRIER();

#define BIG_LAYER(HIN, HOUT, OFFW, BIAS, PF) \
  gemm_compute<8,8,0,0,8,2>(HIN, nullptr, g_w + OFFW, BIAS, bb, acc4, lane, wid); \
  PF; \
  store_acc<2,true>(acc4, HOUT, lane, wid); \
  LAYER_BARRIER();

  BIG_LAYER(Ha, Hb, OFF_W1, b1, (prefetch_b0<8,2>(g_w + OFF_W2, bb, lane, wid)))
  BIG_LAYER(Hb, Ha, OFF_W2, b2, (prefetch_b0<8,2>(g_w + OFF_W3, bb, lane, wid)))
  BIG_LAYER(Ha, Hb, OFF_W3, b3, (prefetch_b0<8,2>(g_w + OFF_W4, bb, lane, wid)))
  BIG_LAYER(Hb, Ha, OFF_W4, b4, (prefetch_b0<10,2>(g_w + OFF_W5, bb, lane, wid)))

  // L5: concat [h(256)=Ha | x(63)+pad=Xb] -> Hb   (last use of Xb x-data)
  gemm_compute<8,8,2,2,10,2>(Ha, Xb, g_w + OFF_W5, b5, bb, acc4, lane, wid);
  prefetch_b0<8,2>(g_w + OFF_W6, bb, lane, wid);
  store_acc<2,true>(acc4, Hb, lane, wid);
  LAYER_BARRIER();

  BIG_LAYER(Hb, Ha, OFF_W6, b6, (prefetch_b0<8,2>(g_w + OFF_W7, bb, lane, wid)))

  // L7: Ha -> Hb + fused sigma partials (Sb lives in dead Xb region)
  gemm_compute<8,8,0,0,8,2>(Ha, nullptr, g_w + OFF_W7, b7, bb, acc4, lane, wid);
  prefetch_b0<8,2>(g_w + OFF_W8, bb, lane, wid);
  store_acc_sigma(acc4, Hb, Sb, lane, wid);
  LAYER_BARRIER();

  // finish sigma: 64 threads, Sb stable from here on
  if (tid < 64) {
    float s = bsig[0];
#pragma unroll
    for (int w = 0; w < 8; ++w)
      s += Sb[w * 64 + tid];
    float sp = (s > 0.f) ? (s + log1pf(expf(-s))) : log1pf(expf(s));
    out[3 * NB + rowbase + tid] = sp;
  }

  // L8 (bottleneck, no relu): Hb -> Ha
  gemm_compute<8,8,0,0,8,2>(Hb, nullptr, g_w + OFF_W8, b8, bb, acc4, lane, wid);
  prefetch_b0<9,1>(g_w + OFF_W9, bb, lane, wid);
  store_acc<2,false>(acc4, Ha, lane, wid);
  LAYER_BARRIER();

  // L9: concat [h8(256)=Ha | d(27)+pad=Db] -> Hb (NT=1: 16 cols/wave)
  gemm_compute<8,8,1,1,9,1>(Ha, Db, g_w + OFF_W9, b9, bb, acc1, lane, wid);
  prefetch_b0<4,1>(g_w + OFF_W10, bb, lane, wid);
  store_acc<1,true>(acc1, Hb, lane, wid);
  LAYER_BARRIER();

#define SMALL_LAYER(HIN, HOUT, OFFW, BIAS, PF) \
  gemm_compute<4,8,0,0,4,1>(HIN, nullptr, g_w + OFFW, BIAS, bb, acc1, lane, wid); \
  PF; \
  store_acc<1,true>(acc1, HOUT, lane, wid); \
  LAYER_BARRIER();

  SMALL_LAYER(Hb, Ha, OFF_W10, b10, (prefetch_b0<4,1>(g_w + OFF_W11, bb, lane, wid)))
  SMALL_LAYER(Ha, Hb, OFF_W11, b11, (prefetch_b0<4,1>(g_w + OFF_W12, bb, lane, wid)))

  // L12: Hb -> rgb head only (h12 never touches LDS; Rb in dead Xb region)
  gemm_compute<4,8,0,0,4,1>(Hb, nullptr, g_w + OFF_W12, b12, bb, acc1, lane, wid);
  rgb_partial(acc1, Rb, lane, wid);
  LAYER_BARRIER();

  if (tid < 192) {
    const int r = tid / 3;
    const int ch = tid - r * 3;
    const int rt = r >> 4;
    const int l15r = r & 15;
    float s = brgb[ch];
#pragma unroll
    for (int w = 0; w < 8; ++w)
      s += Rb[((w * 4 + rt) * 3 + ch) * 16 + l15r];
    float val = 1.f / (1.f + expf(-s));
    out[(size_t)(rowbase + r) * 3 + ch] = val;
  }
}

extern "C" void kernel_launch(void* const* d_in, const int* in_sizes, int n_in,
                              void* d_out, int out_size, void* d_ws, size_t ws_size,
                              hipStream_t stream) {
  const float* x    = (const float*)d_in[0];
  const float* dd   = (const float*)d_in[1];
  const float* W0   = (const float*)d_in[2];
  const float* b0   = (const float*)d_in[3];
  const float* W1   = (const float*)d_in[4];
  const float* b1   = (const float*)d_in[5];
  const float* W2   = (const float*)d_in[6];
  const float* b2   = (const float*)d_in[7];
  const float* W3   = (const float*)d_in[8];
  const float* b3   = (const float*)d_in[9];
  const float* W4   = (const float*)d_in[10];
  const float* b4   = (const float*)d_in[11];
  const float* W5   = (const float*)d_in[12];
  const float* b5   = (const float*)d_in[13];
  const float* W6   = (const float*)d_in[14];
  const float* b6   = (const float*)d_in[15];
  const float* W7   = (const float*)d_in[16];
  const float* b7   = (const float*)d_in[17];
  const float* Wsig = (const float*)d_in[18];
  const float* bsig = (const float*)d_in[19];
  const float* W8   = (const float*)d_in[20];
  const float* b8   = (const float*)d_in[21];
  const float* W9   = (const float*)d_in[22];
  const float* b9   = (const float*)d_in[23];
  const float* W10  = (const float*)d_in[24];
  const float* b10  = (const float*)d_in[25];
  const float* W11  = (const float*)d_in[26];
  const float* b11  = (const float*)d_in[27];
  const float* W12  = (const float*)d_in[28];
  const float* b12  = (const float*)d_in[29];
  const float* Wrgb = (const float*)d_in[30];
  const float* brgb = (const float*)d_in[31];

  prep_kernel<<<(WTOTAL + 255) / 256, 256, 0, stream>>>(
      W0, W1, W2, W3, W4, W5, W6, W7, Wsig, W8, W9, W10, W11, W12, Wrgb);

  nerf_main<<<NB / RTILE, 512, 0, stream>>>(
      x, dd, b0, b1, b2, b3, b4, b5, b6, b7, bsig, b8, b9, b10, b11, b12, brgb,
      (float*)d_out);
}

// Round 20
// 300.292 us; speedup vs baseline: 3.3457x; 1.0439x over previous
//
#include <hip/hip_runtime.h>
#include <hip/hip_bf16.h>

#define NB 262144
#define RTILE 64

typedef __bf16 bf16x8 __attribute__((ext_vector_type(8)));
typedef float f32x4 __attribute__((ext_vector_type(4)));

// ---- packed bf16 weight buffer ----
// MFMA layers fragment-ordered: fragment (colTile,ks) at
//   off + ((colTile*KSTRIDE + ks)*64 + lane)*8
// lane's elems: W[col=colTile*16+(lane&15)][k=ks*32+(lane>>4)*8+e].
// Wsig/Wrgb plain row-major.
#define OFF_W0   0        // [256][64]   (K 63->64)
#define OFF_W1   16384    // [256][256]
#define OFF_W2   81920
#define OFF_W3   147456
#define OFF_W4   212992
#define OFF_W5   278528   // [256][320]  (K 319->320; ks 8,9 = x)
#define OFF_W6   360448
#define OFF_W7   425984
#define OFF_WSIG 491520   // [1][256] plain
#define OFF_W8   491776   // [256][256]
#define OFF_W9   557312   // [128][288]  (K 283->288; ks 8 = d)
#define OFF_W10  594176   // [128][128]
#define OFF_W11  610560
#define OFF_W12  626944
#define OFF_WRGB 643328   // [3][128] plain
#define WTOTAL   643712

__device__ __align__(16) unsigned short g_w[WTOTAL];

__device__ __forceinline__ unsigned short f2bfu(float f) {
  __bf16 h = (__bf16)f;
  return __builtin_bit_cast(unsigned short, h);
}
__device__ __forceinline__ float bfu2f(unsigned short u) {
  return (float)__builtin_bit_cast(__bf16, u);
}

// Hand barrier: orders LDS producer->consumer (lgkmcnt(0)) WITHOUT draining
// vmcnt -- cross-layer weight prefetch loads stay in flight.
// sched_barrier(0) fences compiler motion across it (rule #18).
#define LAYER_BARRIER() do { \
  asm volatile("s_waitcnt lgkmcnt(0)\n\ts_barrier" ::: "memory"); \
  __builtin_amdgcn_sched_barrier(0); \
} while (0)

__global__ void prep_kernel(const float* W0, const float* W1, const float* W2,
                            const float* W3, const float* W4, const float* W5,
                            const float* W6, const float* W7, const float* Wsig,
                            const float* W8, const float* W9, const float* W10,
                            const float* W11, const float* W12, const float* Wrgb) {
  const float* srcs[15] = {W0,W1,W2,W3,W4,W5,W6,W7,Wsig,W8,W9,W10,W11,W12,Wrgb};
  const int dsto[16] = {OFF_W0,OFF_W1,OFF_W2,OFF_W3,OFF_W4,OFF_W5,OFF_W6,OFF_W7,
                        OFF_WSIG,OFF_W8,OFF_W9,OFF_W10,OFF_W11,OFF_W12,OFF_WRGB,WTOTAL};
  const int kpad[15] = {64,256,256,256,256,320,256,256,256,256,288,128,128,128,128};
  const int ksrc[15] = {63,256,256,256,256,319,256,256,256,256,283,128,128,128,128};
  int idx = blockIdx.x * blockDim.x + threadIdx.x;
  if (idx >= WTOTAL) return;
  int r = 0;
  for (int i = 1; i < 15; ++i) if (idx >= dsto[i]) r = i;
  int local = idx - dsto[r];
  float v;
  if (r == 8 || r == 14) {             // head weights: plain row-major
    int o = local / kpad[r];
    int k = local - o * kpad[r];
    v = (k < ksrc[r]) ? srcs[r][o * ksrc[r] + k] : 0.0f;
  } else {                             // MFMA layers: fragment-ordered
    const int KS = kpad[r] >> 5;
    int frag = local >> 9;
    int within = local & 511;
    int lane = within >> 3;
    int e = within & 7;
    int colTile = frag / KS;
    int ks = frag - colTile * KS;
    int col = colTile * 16 + (lane & 15);
    int k = ks * 32 + (lane >> 4) * 8 + e;
    v = (k < ksrc[r]) ? srcs[r][col * ksrc[r] + k] : 0.0f;
  }
  g_w[idx] = f2bfu(v);
}

// ---- fused MLP ----
// Final structure (best measured ~300 us, 1.12 PF effective, 54% of the
// 2075 TF 16x16x32-MFMA ceiling; MfmaUtil+VALUBusy ~= 99% -> issue-port
// saturated at the structural-minimum instruction mix):
// - fragment-ordered LDS for H/Xb/Db: lane-linear conflict-free b128 A-reads
//   with SGPR-base + compile-time-immediate addressing (r12)
// - copy-free parity K-loop pipeline: b[2][NT] global-weight prefetch and
//   a[2][4] LDS prefetch, static kk&1 indices, setprio(1) around MFMAs (r13/r15)
// - bias folded into accumulator init (C-in of first MFMA)
// - cross-layer weight prefetch surviving lgkm-only barriers (r16)
// - swapped-operand MFMA (r9): acc = mfma(W_frag, H_frag) -> lane holds
//   row rt*16+l15, cols ct*16+l4*4+0..3 -> one b64 store per (rt,ct)
// - sigma/rgb heads fused into register epilogues (r10)
template<int KSTRIDE, int NT>
__device__ __forceinline__ void prefetch_b0(
    const unsigned short* Wp, bf16x8 (&b)[2][4], int lane, int wid)
{
  const unsigned short* wb = Wp + (size_t)(wid * NT) * KSTRIDE * 512 + lane * 8;
#pragma unroll
  for (int ct = 0; ct < NT; ++ct)
    b[0][ct] = *(const bf16x8*)&wb[(size_t)(ct * KSTRIDE) * 512];
}

template<int KS1, int KSA1, int KS2, int KSA2, int KSTRIDE, int NT>
__device__ __forceinline__ void gemm_compute(
    const unsigned short* A1,
    const unsigned short* A2,
    const unsigned short* Wp,
    const float* bias,
    bf16x8 (&b)[2][4],                  // b[0][0..NT-1] preloaded by caller
    f32x4 (&acc)[4][NT],
    int lane, int wid)
{
  constexpr int KS = KS1 + KS2;
  const int l4 = lane >> 4;
  const unsigned short* wb = Wp + (size_t)(wid * NT) * KSTRIDE * 512 + lane * 8;
  const unsigned short* a1 = A1 + lane * 8;
  const unsigned short* a2 = A2 ? (A2 + lane * 8) : nullptr;

  // bias-folded accumulator init
#pragma unroll
  for (int ct = 0; ct < NT; ++ct) {
    const f32x4 bv = *(const f32x4*)&bias[wid * (NT * 16) + ct * 16 + l4 * 4];
#pragma unroll
    for (int rt = 0; rt < 4; ++rt)
      acc[rt][ct] = bv;
  }

  bf16x8 a[2][4];
#pragma unroll
  for (int rt = 0; rt < 4; ++rt)
    a[0][rt] = *(const bf16x8*)&a1[(rt * KSA1) * 512];

#pragma unroll
  for (int kk = 0; kk < KS; ++kk) {
    // prefetch kk+1 into the other parity slot (no copies, static indices)
    if (kk + 1 < KS) {
#pragma unroll
      for (int ct = 0; ct < NT; ++ct)
        b[(kk + 1) & 1][ct] = *(const bf16x8*)&wb[(size_t)(ct * KSTRIDE + kk + 1) * 512];
#pragma unroll
      for (int rt = 0; rt < 4; ++rt) {
        if (kk + 1 < KS1)
          a[(kk + 1) & 1][rt] = *(const bf16x8*)&a1[(rt * KSA1 + kk + 1) * 512];
        else
          a[(kk + 1) & 1][rt] = *(const bf16x8*)&a2[(rt * KSA2 + (kk + 1 - KS1)) * 512];
      }
    }
    __builtin_amdgcn_s_setprio(1);
#pragma unroll
    for (int rt = 0; rt < 4; ++rt)
#pragma unroll
      for (int ct = 0; ct < NT; ++ct)
        acc[rt][ct] = __builtin_amdgcn_mfma_f32_16x16x32_bf16(
            b[kk & 1][ct], a[kk & 1][rt], acc[rt][ct], 0, 0, 0);
    __builtin_amdgcn_s_setprio(0);
  }
}

// Store acc (already biased) into fragment-ordered H (KSH=8 stride).
template<int NT, bool RELU>
__device__ __forceinline__ void store_acc(
    const f32x4 (&acc)[4][NT],
    unsigned short* Out, int lane, int wid)
{
  const int l15 = lane & 15;
  const int l4  = lane >> 4;
  const int colbase = wid * (NT * 16);
#pragma unroll
  for (int ct = 0; ct < NT; ++ct) {
    const int c0 = colbase + ct * 16 + l4 * 4;
    const int f  = c0 >> 5;
    const int li = l15 + 16 * ((c0 >> 3) & 3);
    const int e0 = c0 & 7;
#pragma unroll
    for (int rt = 0; rt < 4; ++rt) {
      float v0 = acc[rt][ct][0];
      float v1 = acc[rt][ct][1];
      float v2 = acc[rt][ct][2];
      float v3 = acc[rt][ct][3];
      if (RELU) {
        v0 = fmaxf(v0, 0.f); v1 = fmaxf(v1, 0.f);
        v2 = fmaxf(v2, 0.f); v3 = fmaxf(v3, 0.f);
      }
      uint2 u;
      u.x = (unsigned)f2bfu(v0) | ((unsigned)f2bfu(v1) << 16);
      u.y = (unsigned)f2bfu(v2) | ((unsigned)f2bfu(v3) << 16);
      *(uint2*)&Out[(rt * 8 + f) * 512 + li * 8 + e0] = u;
    }
  }
}

// L7 store + fused sigma partials (h7 . Wsig); acc already biased.
__device__ __forceinline__ void store_acc_sigma(
    const f32x4 (&acc)[4][4],
    unsigned short* Out, float* Sb, int lane, int wid)
{
  const int l15 = lane & 15;
  const int l4  = lane >> 4;
  const int colbase = wid * 64;
  float ps[4] = {0.f, 0.f, 0.f, 0.f};
#pragma unroll
  for (int ct = 0; ct < 4; ++ct) {
    const int c0 = colbase + ct * 16 + l4 * 4;
    const int f  = c0 >> 5;
    const int li = l15 + 16 * ((c0 >> 3) & 3);
    const int e0 = c0 & 7;
    const ushort4 wu = *(const ushort4*)&g_w[OFF_WSIG + c0];
    const float w0 = bfu2f(wu.x), w1 = bfu2f(wu.y), w2 = bfu2f(wu.z), w3 = bfu2f(wu.w);
#pragma unroll
    for (int rt = 0; rt < 4; ++rt) {
      float v0 = fmaxf(acc[rt][ct][0], 0.f);
      float v1 = fmaxf(acc[rt][ct][1], 0.f);
      float v2 = fmaxf(acc[rt][ct][2], 0.f);
      float v3 = fmaxf(acc[rt][ct][3], 0.f);
      uint2 u;
      u.x = (unsigned)f2bfu(v0) | ((unsigned)f2bfu(v1) << 16);
      u.y = (unsigned)f2bfu(v2) | ((unsigned)f2bfu(v3) << 16);
      *(uint2*)&Out[(rt * 8 + f) * 512 + li * 8 + e0] = u;
      ps[rt] += bfu2f(f2bfu(v0)) * w0 + bfu2f(f2bfu(v1)) * w1
              + bfu2f(f2bfu(v2)) * w2 + bfu2f(f2bfu(v3)) * w3;
    }
  }
#pragma unroll
  for (int rt = 0; rt < 4; ++rt) {
    ps[rt] += __shfl_xor(ps[rt], 16);
    ps[rt] += __shfl_xor(ps[rt], 32);
  }
  if (l4 == 0) {
#pragma unroll
    for (int rt = 0; rt < 4; ++rt)
      Sb[wid * 64 + rt * 16 + l15] = ps[rt];
  }
}

// L12 epilogue: rgb partials straight from acc2 (already biased).
__device__ __forceinline__ void rgb_partial(
    const f32x4 (&acc)[4][2],
    float* Rb, int lane, int wid)
{
  const int l15 = lane & 15;
  const int l4  = lane >> 4;
  const int colbase = wid * 32;
  float pr[4][3] = {};
#pragma unroll
  for (int ct = 0; ct < 2; ++ct) {
    const int c0 = colbase + ct * 16 + l4 * 4;
    float wf[3][4];
#pragma unroll
    for (int ch = 0; ch < 3; ++ch) {
      const ushort4 wu = *(const ushort4*)&g_w[OFF_WRGB + ch * 128 + c0];
      wf[ch][0] = bfu2f(wu.x); wf[ch][1] = bfu2f(wu.y);
      wf[ch][2] = bfu2f(wu.z); wf[ch][3] = bfu2f(wu.w);
    }
#pragma unroll
    for (int rt = 0; rt < 4; ++rt) {
      float v0 = fmaxf(acc[rt][ct][0], 0.f);
      float v1 = fmaxf(acc[rt][ct][1], 0.f);
      float v2 = fmaxf(acc[rt][ct][2], 0.f);
      float v3 = fmaxf(acc[rt][ct][3], 0.f);
#pragma unroll
      for (int ch = 0; ch < 3; ++ch)
        pr[rt][ch] += v0 * wf[ch][0] + v1 * wf[ch][1] + v2 * wf[ch][2] + v3 * wf[ch][3];
    }
  }
#pragma unroll
  for (int rt = 0; rt < 4; ++rt)
#pragma unroll
    for (int ch = 0; ch < 3; ++ch) {
      pr[rt][ch] += __shfl_xor(pr[rt][ch], 16);
      pr[rt][ch] += __shfl_xor(pr[rt][ch], 32);
    }
  if (l4 == 0) {
#pragma unroll
    for (int rt = 0; rt < 4; ++rt)
#pragma unroll
      for (int ch = 0; ch < 3; ++ch)
        Rb[((wid * 4 + rt) * 3 + ch) * 16 + l15] = pr[rt][ch];
  }
}

__launch_bounds__(256, 3)
__global__ void nerf_main(const float* __restrict__ x, const float* __restrict__ d,
    const float* b0, const float* b1, const float* b2, const float* b3,
    const float* b4, const float* b5, const float* b6, const float* b7,
    const float* bsig, const float* b8, const float* b9, const float* b10,
    const float* b11, const float* b12, const float* brgb,
    float* __restrict__ out)
{
  __shared__ __align__(16) unsigned short H[64 * 256];   // 32768 B, fragment-ordered KSH=8
  __shared__ __align__(16) unsigned short Xb[64 * 64];   // 8192 B, fragment-ordered KSX=2
  __shared__ __align__(16) unsigned short Db[64 * 32];   // 4096 B, fragment-ordered KSD=1
  __shared__ float Sb[256];                // 1024 B sigma partials
  __shared__ float Rb[768];                // 3072 B rgb partials
  // total 49152 B -> 3 blocks/CU

  const int tid = threadIdx.x;
  const int lane = tid & 63;
  const int wid = tid >> 6;
  const int rowbase = blockIdx.x * RTILE;

  bf16x8 bb[2][4];
  f32x4 acc4[4][4];
  f32x4 acc2[4][2];

  // prefetch W0 kk=0 frags first -- overlaps the staging phase
  prefetch_b0<2,4>(g_w + OFF_W0, bb, lane, wid);

  // ---- stage x and d tiles (fp32 -> bf16, fragment-ordered writes) ----
  {
    const int r = tid >> 2;      // 0..63
    const int sub = tid & 3;
    const int rt = r >> 4;
    const int rl = r & 15;
    const float* xr = x + (size_t)(rowbase + r) * 63;
    for (int j = 0; j < 16; ++j) {
      const int c = sub + j * 4;        // 0..63
      const unsigned short v = (c < 63) ? f2bfu(xr[c]) : (unsigned short)0;
      Xb[(rt * 2 + (c >> 5)) * 512 + (rl + 16 * ((c >> 3) & 3)) * 8 + (c & 7)] = v;
    }
    const float* dr = d + (size_t)(rowbase + r) * 27;
    for (int j = 0; j < 8; ++j) {
      const int c = sub + j * 4;        // 0..31
      const unsigned short v = (c < 27) ? f2bfu(dr[c]) : (unsigned short)0;
      Db[rt * 512 + (rl + 16 * ((c >> 3) & 3)) * 8 + (c & 7)] = v;
    }
  }
  LAYER_BARRIER();

  // L0: reads Xb only -> write H directly (first writer)
  gemm_compute<2,2,0,0,2,4>(Xb, nullptr, g_w + OFF_W0, b0, bb, acc4, lane, wid);
  prefetch_b0<8,4>(g_w + OFF_W1, bb, lane, wid);
  store_acc<4,true>(acc4, H, lane, wid);
  LAYER_BARRIER();

#define BIG_LAYER(OFFW, BIAS, PF) \
  gemm_compute<8,8,0,0,8,4>(H, nullptr, g_w + OFFW, BIAS, bb, acc4, lane, wid); \
  PF; \
  LAYER_BARRIER(); \
  store_acc<4,true>(acc4, H, lane, wid); \
  LAYER_BARRIER();

  BIG_LAYER(OFF_W1, b1, (prefetch_b0<8,4>(g_w + OFF_W2, bb, lane, wid)))
  BIG_LAYER(OFF_W2, b2, (prefetch_b0<8,4>(g_w + OFF_W3, bb, lane, wid)))
  BIG_LAYER(OFF_W3, b3, (prefetch_b0<8,4>(g_w + OFF_W4, bb, lane, wid)))
  BIG_LAYER(OFF_W4, b4, (prefetch_b0<10,4>(g_w + OFF_W5, bb, lane, wid)))

  // L5: concat [h(256) | x(63)+pad] -> K=320
  gemm_compute<8,8,2,2,10,4>(H, Xb, g_w + OFF_W5, b5, bb, acc4, lane, wid);
  prefetch_b0<8,4>(g_w + OFF_W6, bb, lane, wid);
  LAYER_BARRIER();
  store_acc<4,true>(acc4, H, lane, wid);
  LAYER_BARRIER();

  BIG_LAYER(OFF_W6, b6, (prefetch_b0<8,4>(g_w + OFF_W7, bb, lane, wid)))

  // L7 + fused sigma partials
  gemm_compute<8,8,0,0,8,4>(H, nullptr, g_w + OFF_W7, b7, bb, acc4, lane, wid);
  prefetch_b0<8,4>(g_w + OFF_W8, bb, lane, wid);
  LAYER_BARRIER();
  store_acc_sigma(acc4, H, Sb, lane, wid);
  LAYER_BARRIER();

  // finish sigma: 64 threads, Sb stable from here on
  if (tid < 64) {
    float s = Sb[tid] + Sb[64 + tid] + Sb[128 + tid] + Sb[192 + tid] + bsig[0];
    float sp = (s > 0.f) ? (s + log1pf(expf(-s))) : log1pf(expf(s));
    out[3 * NB + rowbase + tid] = sp;
  }

  // L8 (bottleneck, no relu)
  gemm_compute<8,8,0,0,8,4>(H, nullptr, g_w + OFF_W8, b8, bb, acc4, lane, wid);
  prefetch_b0<9,2>(g_w + OFF_W9, bb, lane, wid);
  LAYER_BARRIER();
  store_acc<4,false>(acc4, H, lane, wid);
  LAYER_BARRIER();

  // L9: concat [h8(256) | d(27)+pad] -> K=288, N=128 (d from Db)
  gemm_compute<8,8,1,1,9,2>(H, Db, g_w + OFF_W9, b9, bb, acc2, lane, wid);
  prefetch_b0<4,2>(g_w + OFF_W10, bb, lane, wid);
  LAYER_BARRIER();
  store_acc<2,true>(acc2, H, lane, wid);
  LAYER_BARRIER();

#define SMALL_LAYER(OFFW, BIAS, PF) \
  gemm_compute<4,8,0,0,4,2>(H, nullptr, g_w + OFFW, BIAS, bb, acc2, lane, wid); \
  PF; \
  LAYER_BARRIER(); \
  store_acc<2,true>(acc2, H, lane, wid); \
  LAYER_BARRIER();

  SMALL_LAYER(OFF_W10, b10, (prefetch_b0<4,2>(g_w + OFF_W11, bb, lane, wid)))
  SMALL_LAYER(OFF_W11, b11, (prefetch_b0<4,2>(g_w + OFF_W12, bb, lane, wid)))

  // L12 + fused rgb head: h12 never touches LDS
  gemm_compute<4,8,0,0,4,2>(H, nullptr, g_w + OFF_W12, b12, bb, acc2, lane, wid);
  rgb_partial(acc2, Rb, lane, wid);
  LAYER_BARRIER();

  if (tid < 192) {
    const int r = tid / 3;
    const int ch = tid - r * 3;
    const int rt = r >> 4;
    const int l15r = r & 15;
    float s = brgb[ch];
#pragma unroll
    for (int w = 0; w < 4; ++w)
      s += Rb[((w * 4 + rt) * 3 + ch) * 16 + l15r];
    float val = 1.f / (1.f + expf(-s));
    out[(size_t)(rowbase + r) * 3 + ch] = val;
  }
}

extern "C" void kernel_launch(void* const* d_in, const int* in_sizes, int n_in,
                              void* d_out, int out_size, void* d_ws, size_t ws_size,
                              hipStream_t stream) {
  const float* x    = (const float*)d_in[0];
  const float* dd   = (const float*)d_in[1];
  const float* W0   = (const float*)d_in[2];
  const float* b0   = (const float*)d_in[3];
  const float* W1   = (const float*)d_in[4];
  const float* b1   = (const float*)d_in[5];
  const float* W2   = (const float*)d_in[6];
  const float* b2   = (const float*)d_in[7];
  const float* W3   = (const float*)d_in[8];
  const float* b3   = (const float*)d_in[9];
  const float* W4   = (const float*)d_in[10];
  const float* b4   = (const float*)d_in[11];
  const float* W5   = (const float*)d_in[12];
  const float* b5   = (const float*)d_in[13];
  const float* W6   = (const float*)d_in[14];
  const float* b6   = (const float*)d_in[15];
  const float* W7   = (const float*)d_in[16];
  const float* b7   = (const float*)d_in[17];
  const float* Wsig = (const float*)d_in[18];
  const float* bsig = (const float*)d_in[19];
  const float* W8   = (const float*)d_in[20];
  const float* b8   = (const float*)d_in[21];
  const float* W9   = (const float*)d_in[22];
  const float* b9   = (const float*)d_in[23];
  const float* W10  = (const float*)d_in[24];
  const float* b10  = (const float*)d_in[25];
  const float* W11  = (const float*)d_in[26];
  const float* b11  = (const float*)d_in[27];
  const float* W12  = (const float*)d_in[28];
  const float* b12  = (const float*)d_in[29];
  const float* Wrgb = (const float*)d_in[30];
  const float* brgb = (const float*)d_in[31];

  prep_kernel<<<(WTOTAL + 255) / 256, 256, 0, stream>>>(
      W0, W1, W2, W3, W4, W5, W6, W7, Wsig, W8, W9, W10, W11, W12, Wrgb);

  nerf_main<<<NB / RTILE, 256, 0, stream>>>(
      x, dd, b0, b1, b2, b3, b4, b5, b6, b7, bsig, b8, b9, b10, b11, b12, brgb,
      (float*)d_out);
}